// Round 1
// baseline (371.072 us; speedup 1.0000x reference)
//
#include <hip/hip_runtime.h>

// Problem constants (from reference setup_inputs): B=4, S=8192, D=1024, fp32.
constexpr int B  = 4;
constexpr int S  = 8192;
constexpr int D  = 1024;
constexpr int C  = 128;        // chunks along S
constexpr int L  = S / C;      // 64 steps per chunk
constexpr int D4 = D / 4;      // 256 float4 per (b, s) row — exactly one 256-thread block

// ---------------- Phase 1: per-chunk aggregates ----------------
// Block (c, b): scan chunk c of batch b. Thread t owns float4 of 4 channels.
// Computes X = chunk-combine result with h_in = 0, A = prod(alpha) over chunk.
__global__ __launch_bounds__(256) void phase1(const float4* __restrict__ x,
                                              const float4* __restrict__ a,
                                              float4* __restrict__ Xagg,
                                              float4* __restrict__ Aagg) {
    const int t = threadIdx.x;         // 0..255
    const int c = blockIdx.x;          // chunk
    const int b = blockIdx.y;          // batch
    long base = ((long)(b * S + c * L)) * D4 + t;

    float4 X = {0.f, 0.f, 0.f, 0.f};
    float4 A = {1.f, 1.f, 1.f, 1.f};
    #pragma unroll 8
    for (int s = 0; s < L; ++s) {
        float4 xv = x[base + (long)s * D4];
        float4 av = a[base + (long)s * D4];
        X.x = fmaf(av.x, X.x, xv.x);
        X.y = fmaf(av.y, X.y, xv.y);
        X.z = fmaf(av.z, X.z, xv.z);
        X.w = fmaf(av.w, X.w, xv.w);
        A.x *= av.x; A.y *= av.y; A.z *= av.z; A.w *= av.w;
    }
    long o = ((long)(b * C + c)) * D4 + t;
    Xagg[o] = X;
    Aagg[o] = A;
}

// ---------------- Phase 2: scan across chunk aggregates ----------------
// One thread per scalar channel (b, d). Overwrites Xagg with the EXCLUSIVE
// prefix: the h value entering chunk c. carry_{c} = A_c*carry_{c-1} + X_c.
__global__ __launch_bounds__(256) void phase2(float* __restrict__ Xagg,
                                              const float* __restrict__ Aagg) {
    const int g = blockIdx.x * blockDim.x + threadIdx.x;  // 0..B*D-1
    const int b = g / D;
    const int d = g % D;
    long base = (long)b * C * D + d;
    float carry = 0.f;
    for (int c = 0; c < C; ++c) {
        long o = base + (long)c * D;
        float X = Xagg[o];
        float A = Aagg[o];
        Xagg[o] = carry;            // exclusive prefix for chunk c
        carry = fmaf(A, carry, X);
    }
}

// ---------------- Phase 3: re-scan chunks with incoming prefix ----------------
__global__ __launch_bounds__(256) void phase3(const float4* __restrict__ x,
                                              const float4* __restrict__ a,
                                              const float4* __restrict__ prefix,
                                              float4* __restrict__ out) {
    const int t = threadIdx.x;
    const int c = blockIdx.x;
    const int b = blockIdx.y;

    float4 h = prefix[((long)(b * C + c)) * D4 + t];
    long base = ((long)(b * S + c * L)) * D4 + t;
    #pragma unroll 8
    for (int s = 0; s < L; ++s) {
        float4 xv = x[base + (long)s * D4];
        float4 av = a[base + (long)s * D4];
        h.x = fmaf(av.x, h.x, xv.x);
        h.y = fmaf(av.y, h.y, xv.y);
        h.z = fmaf(av.z, h.z, xv.z);
        h.w = fmaf(av.w, h.w, xv.w);
        out[base + (long)s * D4] = h;
    }
}

extern "C" void kernel_launch(void* const* d_in, const int* in_sizes, int n_in,
                              void* d_out, int out_size, void* d_ws, size_t ws_size,
                              hipStream_t stream) {
    const float4* x = (const float4*)d_in[0];
    const float4* a = (const float4*)d_in[1];
    float4* out = (float4*)d_out;

    // Workspace layout: Xagg (B*C*D floats) | Aagg (B*C*D floats) = 2 MiB each.
    float* Xagg = (float*)d_ws;
    float* Aagg = Xagg + (size_t)B * C * D;

    dim3 grid1(C, B);
    phase1<<<grid1, 256, 0, stream>>>(x, a, (float4*)Xagg, (float4*)Aagg);

    phase2<<<(B * D) / 256, 256, 0, stream>>>(Xagg, Aagg);

    phase3<<<grid1, 256, 0, stream>>>(x, a, (const float4*)Xagg, out);
}